// Round 8
// baseline (523.861 us; speedup 1.0000x reference)
//
#include <hip/hip_runtime.h>
#include <hip/hip_bf16.h>

#define M_DIM 4096
#define K_DIM 4096
#define N_DIM 16384
#define BM 256
#define BN 256
#define BKB 128                    // K-bytes (=int8 elems) per tile
#define NT (K_DIM / BKB)           // 32 K-tiles
#define ATILE_B (BM * BKB)         // 32768 B per A tile
#define LDS_BYTES (2 * ATILE_B)    // 65536 B (A double-buffer only)

using i32x4 = __attribute__((ext_vector_type(4))) int;

// ---------- weight conversion: int32 (harness) -> fragment-linear int8 ----
// Wt fragment f = n16*64 + kt64 (n16 = n/16, kt64 = k/64) is 1KB, lane-
// ordered: Wt[f*1024 + l*16 + j] = W[n16*16 + (l&15)][kt64*64 + (l>>4)*16 + j]
// so a wave's buffer_load_dwordx4 at (f<<10) + lane*16 is a coalesced 1KB
// burst delivering exactly the mfma_i32_16x16x64_i8 B-operand fragment.
__global__ __launch_bounds__(256) void cvt_w_kernel(
    const int* __restrict__ w, signed char* __restrict__ o) {
    int gid  = blockIdx.x * 256 + threadIdx.x;   // one 16B chunk per thread
    int l    = gid & 63;
    int frag = gid >> 6;
    int kt64 = frag & 63;
    int n16  = frag >> 6;
    int n = n16 * 16 + (l & 15);
    int k = kt64 * 64 + (l >> 4) * 16;
    const int* src = w + (size_t)n * K_DIM + k;
    int4 a = *reinterpret_cast<const int4*>(src + 0);
    int4 b = *reinterpret_cast<const int4*>(src + 4);
    int4 c = *reinterpret_cast<const int4*>(src + 8);
    int4 d = *reinterpret_cast<const int4*>(src + 12);
    int4 p;
    p.x = (a.x & 255) | ((a.y & 255) << 8) | ((a.z & 255) << 16) | (a.w << 24);
    p.y = (b.x & 255) | ((b.y & 255) << 8) | ((b.z & 255) << 16) | (b.w << 24);
    p.z = (c.x & 255) | ((c.y & 255) << 8) | ((c.z & 255) << 16) | (c.w << 24);
    p.w = (d.x & 255) | ((d.y & 255) << 8) | ((d.z & 255) << 16) | (d.w << 24);
    *reinterpret_cast<int4*>(o + (size_t)gid * 16) = p;
}

// ---------- x quantization: per-row symmetric int8, scale = rowmax/127 ----
__global__ __launch_bounds__(256) void quant_x_kernel(
    const float* __restrict__ x, signed char* __restrict__ q,
    float* __restrict__ xs) {
    int row = blockIdx.x;
    int tid = threadIdx.x;
    const float* xr = x + (size_t)row * K_DIM + tid * 16;
    float4 v0 = *reinterpret_cast<const float4*>(xr + 0);
    float4 v1 = *reinterpret_cast<const float4*>(xr + 4);
    float4 v2 = *reinterpret_cast<const float4*>(xr + 8);
    float4 v3 = *reinterpret_cast<const float4*>(xr + 12);
    float f[16] = {v0.x, v0.y, v0.z, v0.w, v1.x, v1.y, v1.z, v1.w,
                   v2.x, v2.y, v2.z, v2.w, v3.x, v3.y, v3.z, v3.w};
    float m = 0.f;
    #pragma unroll
    for (int i = 0; i < 16; ++i) m = fmaxf(m, fabsf(f[i]));
    #pragma unroll
    for (int off = 32; off > 0; off >>= 1) m = fmaxf(m, __shfl_xor(m, off));
    __shared__ float red[4];
    if ((tid & 63) == 0) red[tid >> 6] = m;
    __syncthreads();
    m = fmaxf(fmaxf(red[0], red[1]), fmaxf(red[2], red[3]));
    float inv = (m > 0.f) ? 127.0f / m : 0.f;
    if (tid == 0) xs[row] = (m > 0.f) ? m / 127.0f : 0.f;
    int b[16];
    #pragma unroll
    for (int i = 0; i < 16; ++i) {
        float t = f[i] * inv;
        t = fminf(fmaxf(t, -127.f), 127.f);
        b[i] = (int)__builtin_rintf(t);
    }
    int4 p;
    p.x = (b[0] & 255) | ((b[1] & 255) << 8) | ((b[2] & 255) << 16) | (b[3] << 24);
    p.y = (b[4] & 255) | ((b[5] & 255) << 8) | ((b[6] & 255) << 16) | (b[7] << 24);
    p.z = (b[8] & 255) | ((b[9] & 255) << 8) | ((b[10] & 255) << 16) | (b[11] << 24);
    p.w = (b[12] & 255) | ((b[13] & 255) << 8) | ((b[14] & 255) << 16) | (b[15] << 24);
    *reinterpret_cast<int4*>(q + (size_t)row * K_DIM + tid * 16) = p;
}

#define FENCE() asm volatile("" ::: "memory")
#define BARRIER() do { FENCE(); __builtin_amdgcn_s_barrier(); FENCE(); } while (0)

// Read A-half AH's fragments into af[4][2] (8 x ds_read_b128).
// Proven zero-conflict pattern (rounds 5/6): 16-row groups, 2-bit lg chunk,
// chunk XOR (row&7).
#define READ_A(AH)                                                        \
  do { _Pragma("unroll") for (int mi = 0; mi < 4; ++mi) {                 \
    int hr = (AH) * 128 + wm * 64 + mi * 16 + l15;                        \
    const signed char* hb = lb + hr * BKB;                                \
    _Pragma("unroll") for (int kk = 0; kk < 2; ++kk)                      \
      af[mi][kk] = *reinterpret_cast<const i32x4*>(                       \
          hb + (((kk * 4 + lg) ^ (hr & 7)) * 16));                        \
  } } while (0)

// Load B fragments (kk half KK of K-tile T) into SET[2][2] from the
// fragment-linear Wt: 4 coalesced global_load_dwordx4 of 1KB each.
#define LOADB(SET, T, KK)                                                 \
  do { _Pragma("unroll") for (int bg = 0; bg < 2; ++bg)                   \
    _Pragma("unroll") for (int ni = 0; ni < 2; ++ni) {                    \
      int n16 = tn * 16 + bg * 8 + wn * 2 + ni;                           \
      SET[bg][ni] = *reinterpret_cast<const i32x4*>(                      \
          Bt + (((size_t)(n16 * 64 + (T) * 2 + (KK))) << 10) + lane * 16);\
  } } while (0)

// 16-MFMA cluster (A-half AH, K-half KK, B regs BSET), setprio'd (T5).
#define MFMA16(AH, KK, BSET)                                              \
  do { __builtin_amdgcn_s_setprio(1);                                     \
    _Pragma("unroll") for (int bg = 0; bg < 2; ++bg)                      \
      _Pragma("unroll") for (int mi = 0; mi < 4; ++mi)                    \
        _Pragma("unroll") for (int ni = 0; ni < 2; ++ni)                  \
          acc[AH][bg][mi][ni] = __builtin_amdgcn_mfma_i32_16x16x64_i8(    \
              af[mi][KK], BSET[bg][ni], acc[AH][bg][mi][ni], 0, 0, 0);    \
    __builtin_amdgcn_s_setprio(0);                                        \
  } while (0)

// One K-tile: stage A(t+1), load B kk1(t) + B kk0(t+1), two A-half passes
// of 32 MFMA each, vmcnt(0) (loads issued ~1 tile ago -> cheap), barrier.
#define TILE_BODY(BK0CUR, BK0NXT, T)                                      \
  {                                                                       \
    const int s1 = (T) + 1 < NT;                                          \
    const signed char* lb = lds + ((T) & 1) * ATILE_B;                    \
    if (s1) STAGE_A(((T) + 1) & 1, (T) + 1);                              \
    LOADB(bk1, (T), 1);                                                   \
    if (s1) LOADB(BK0NXT, (T) + 1, 0);                                    \
    READ_A(0);                                                            \
    MFMA16(0, 0, BK0CUR);                                                 \
    MFMA16(0, 1, bk1);                                                    \
    READ_A(1);                                                            \
    MFMA16(1, 0, BK0CUR);                                                 \
    MFMA16(1, 1, bk1);                                                    \
    asm volatile("s_waitcnt vmcnt(0)" ::: "memory");                      \
    BARRIER();                                                            \
  }

// C[m][o] = xs[m] * scale[o] * (int dot of Xq[m,:], Wq[o,:]) + bias[o]
// Xq:[M][K] i8 via LDS (A double-buffer, 1 barrier/tile); Wt fragment-linear
// i8 direct global->reg (kk0 prefetched 1 tile ahead); C:[M][N] f32.
__global__ __launch_bounds__(512, 2) void gemm_kernel(
    const signed char* __restrict__ A,
    const signed char* __restrict__ Bt,
    const float* __restrict__ scale,
    const float* __restrict__ xs,
    const float* __restrict__ bias,
    float* __restrict__ C)
{
    extern __shared__ signed char lds[];   // 2 x 32KB A tiles

    // bijective XCD swizzle: nwg = 16*64 = 1024, divisible by 8
    const int nwg = (M_DIM / BM) * (N_DIM / BN);
    const int cpx = nwg / 8;
    int bid = blockIdx.x;
    int swz = (bid & 7) * cpx + (bid >> 3);
    const int ntn = N_DIM / BN;               // 64
    int tm = swz / ntn;
    int tn = swz % ntn;

    int tid  = threadIdx.x;
    int lane = tid & 63;
    int wid  = tid >> 6;      // 8 waves: 2 (M) x 4 (N)
    int wm   = wid >> 2;      // 0..1
    int wn   = wid & 3;       // 0..3
    int l15  = lane & 15;
    int lg   = lane >> 4;     // 0..3

    const signed char* Ab = A + (size_t)tm * BM * K_DIM;

    // Stage the A tile (256 rows x 128B = 32KB) for K-tile t into buffer buf.
    // 4 gload_lds per thread; chunk swizzle ch^(row&7) on the GLOBAL source
    // (rule #21); LDS dest linear.
    auto STAGE_A = [&](int buf, int t) {
        signed char* dbase = lds + buf * ATILE_B;
        #pragma unroll
        for (int i = 0; i < 4; ++i) {
            int flat = i * 512 + tid;            // 16B-chunk id 0..2047
            int row = flat >> 3, ch = flat & 7;
            const signed char* src =
                Ab + (size_t)row * K_DIM + t * BKB + ((ch ^ (row & 7)) * 16);
            __builtin_amdgcn_global_load_lds(
                (const __attribute__((address_space(1))) unsigned int*)src,
                (__attribute__((address_space(3))) unsigned int*)(dbase + flat * 16),
                16, 0, 0);
        }
    };

    i32x4 acc[2][2][4][2];
    #pragma unroll
    for (int a0 = 0; a0 < 2; ++a0)
      #pragma unroll
      for (int g0 = 0; g0 < 2; ++g0)
        #pragma unroll
        for (int mi = 0; mi < 4; ++mi)
          #pragma unroll
          for (int ni = 0; ni < 2; ++ni)
            acc[a0][g0][mi][ni] = (i32x4){0, 0, 0, 0};

    i32x4 af[4][2], bk0A[2][2], bk0B[2][2], bk1[2][2];

    // Prologue: A(0) staged, B kk0(0) loaded; drain, publish.
    STAGE_A(0, 0);
    LOADB(bk0A, 0, 0);
    asm volatile("s_waitcnt vmcnt(0)" ::: "memory");
    BARRIER();

    for (int tt = 0; tt < NT; tt += 2) {
        TILE_BODY(bk0A, bk0B, tt);
        TILE_BODY(bk0B, bk0A, tt + 1);
    }

    // Epilogue: 16x16 C/D layout col = lane&15, row = (lane>>4)*4 + reg (m89)
    #pragma unroll
    for (int AH = 0; AH < 2; ++AH)
      #pragma unroll
      for (int BG = 0; BG < 2; ++BG)
        #pragma unroll
        for (int ni = 0; ni < 2; ++ni) {
            int col = tn * BN + BG * 128 + wn * 32 + ni * 16 + l15;
            float s = scale[col];
            float b = bias[col];
            #pragma unroll
            for (int mi = 0; mi < 4; ++mi) {
                int row0 = tm * BM + AH * 128 + wm * 64 + mi * 16 + lg * 4;
                float4 x4 = *reinterpret_cast<const float4*>(xs + row0);
                float xv[4] = {x4.x, x4.y, x4.z, x4.w};
                #pragma unroll
                for (int r = 0; r < 4; ++r)
                    C[(size_t)(row0 + r) * N_DIM + col] =
                        (float)acc[AH][BG][mi][ni][r] * (s * xv[r]) + b;
            }
        }
}

// safety net if workspace is too small
__global__ void naive_kernel(const float* __restrict__ x,
                             const int* __restrict__ w,
                             const float* __restrict__ scale,
                             const float* __restrict__ bias,
                             float* __restrict__ out) {
    long long idx = (long long)blockIdx.x * blockDim.x + threadIdx.x;
    long long total = (long long)M_DIM * N_DIM;
    if (idx >= total) return;
    int m = (int)(idx / N_DIM);
    int o = (int)(idx % N_DIM);
    const float* xr = x + (size_t)m * K_DIM;
    const int* wr = w + (size_t)o * K_DIM;
    float sum = 0.f;
    for (int k = 0; k < K_DIM; ++k) sum += xr[k] * (float)wr[k];
    out[idx] = sum * scale[o] + bias[o];
}

extern "C" void kernel_launch(void* const* d_in, const int* in_sizes, int n_in,
                              void* d_out, int out_size, void* d_ws, size_t ws_size,
                              hipStream_t stream)
{
    const float* x     = (const float*)d_in[0];
    const int*   w     = (const int*)d_in[1];
    const float* scale = (const float*)d_in[2];
    const float* bias  = (const float*)d_in[3];
    float*       out   = (float*)d_out;

    const size_t needW = (size_t)N_DIM * K_DIM;            // 64MB int8 (retiled)
    const size_t needX = (size_t)M_DIM * K_DIM;            // 16MB int8
    const size_t needS = (size_t)M_DIM * sizeof(float);    // 16KB

    if (ws_size >= needW + needX + needS) {
        signed char* Wt = (signed char*)d_ws;
        signed char* Xq = (signed char*)((char*)d_ws + needW);
        float*       xs = (float*)((char*)d_ws + needW + needX);
        hipLaunchKernelGGL(cvt_w_kernel, dim3((N_DIM / 16) * (K_DIM / 64) / 4),
                           dim3(256), 0, stream, w, Wt);
        hipLaunchKernelGGL(quant_x_kernel, dim3(M_DIM), dim3(256), 0, stream,
                           x, Xq, xs);
        hipLaunchKernelGGL(gemm_kernel, dim3((M_DIM / BM) * (N_DIM / BN)), dim3(512),
                           LDS_BYTES, stream, Xq, Wt, scale, xs, bias, out);
    } else {
        long long total = (long long)M_DIM * N_DIM;
        int blocks = (int)((total + 255) / 256);
        hipLaunchKernelGGL(naive_kernel, dim3(blocks), dim3(256), 0, stream,
                           x, w, scale, bias, out);
    }
}

// Round 9
// 382.951 us; speedup vs baseline: 1.3680x; 1.3680x over previous
//
#include <hip/hip_runtime.h>
#include <hip/hip_bf16.h>

#define M_DIM 4096
#define K_DIM 4096
#define N_DIM 16384
#define BM 256
#define BN 256
#define BKB 128                    // K-bytes (=int8 elems) per tile
#define NT (K_DIM / BKB)           // 32 K-tiles
#define SLOT_B 16384               // bytes per half-slot (128 rows x 128 B)
#define TILE_B (4 * SLOT_B)        // A0,A1,B0,B1 = 64KB per buffer
#define LDS_BYTES (2 * TILE_B)     // 131072 B

using i32x4 = __attribute__((ext_vector_type(4))) int;

// ---------- weight conversion: int32 (harness) -> packed int8 (row-major) --
__global__ void cvt_w_kernel(const int* __restrict__ w,
                             signed char* __restrict__ o, int n) {
    int tid = blockIdx.x * blockDim.x + threadIdx.x;
    int stride = gridDim.x * blockDim.x;
    for (int base = tid * 16; base < n; base += stride * 16) {
        int4 a = *reinterpret_cast<const int4*>(w + base);
        int4 b = *reinterpret_cast<const int4*>(w + base + 4);
        int4 c = *reinterpret_cast<const int4*>(w + base + 8);
        int4 d = *reinterpret_cast<const int4*>(w + base + 12);
        int4 p;
        p.x = (a.x & 255) | ((a.y & 255) << 8) | ((a.z & 255) << 16) | (a.w << 24);
        p.y = (b.x & 255) | ((b.y & 255) << 8) | ((b.z & 255) << 16) | (b.w << 24);
        p.z = (c.x & 255) | ((c.y & 255) << 8) | ((c.z & 255) << 16) | (c.w << 24);
        p.w = (d.x & 255) | ((d.y & 255) << 8) | ((d.z & 255) << 16) | (d.w << 24);
        *reinterpret_cast<int4*>(o + base) = p;
    }
}

// ---------- x quantization: per-row symmetric int8, scale = rowmax/127 ----
__global__ __launch_bounds__(256) void quant_x_kernel(
    const float* __restrict__ x, signed char* __restrict__ q,
    float* __restrict__ xs) {
    int row = blockIdx.x;
    int tid = threadIdx.x;
    const float* xr = x + (size_t)row * K_DIM + tid * 16;
    float4 v0 = *reinterpret_cast<const float4*>(xr + 0);
    float4 v1 = *reinterpret_cast<const float4*>(xr + 4);
    float4 v2 = *reinterpret_cast<const float4*>(xr + 8);
    float4 v3 = *reinterpret_cast<const float4*>(xr + 12);
    float f[16] = {v0.x, v0.y, v0.z, v0.w, v1.x, v1.y, v1.z, v1.w,
                   v2.x, v2.y, v2.z, v2.w, v3.x, v3.y, v3.z, v3.w};
    float m = 0.f;
    #pragma unroll
    for (int i = 0; i < 16; ++i) m = fmaxf(m, fabsf(f[i]));
    #pragma unroll
    for (int off = 32; off > 0; off >>= 1) m = fmaxf(m, __shfl_xor(m, off));
    __shared__ float red[4];
    if ((tid & 63) == 0) red[tid >> 6] = m;
    __syncthreads();
    m = fmaxf(fmaxf(red[0], red[1]), fmaxf(red[2], red[3]));
    float inv = (m > 0.f) ? 127.0f / m : 0.f;
    if (tid == 0) xs[row] = (m > 0.f) ? m / 127.0f : 0.f;
    int b[16];
    #pragma unroll
    for (int i = 0; i < 16; ++i) {
        float t = f[i] * inv;
        t = fminf(fmaxf(t, -127.f), 127.f);
        b[i] = (int)__builtin_rintf(t);
    }
    int4 p;
    p.x = (b[0] & 255) | ((b[1] & 255) << 8) | ((b[2] & 255) << 16) | (b[3] << 24);
    p.y = (b[4] & 255) | ((b[5] & 255) << 8) | ((b[6] & 255) << 16) | (b[7] << 24);
    p.z = (b[8] & 255) | ((b[9] & 255) << 8) | ((b[10] & 255) << 16) | (b[11] << 24);
    p.w = (b[12] & 255) | ((b[13] & 255) << 8) | ((b[14] & 255) << 16) | (b[15] << 24);
    *reinterpret_cast<int4*>(q + (size_t)row * K_DIM + tid * 16) = p;
}

#define FENCE() asm volatile("" ::: "memory")
#define BARRIER() do { FENCE(); __builtin_amdgcn_s_barrier(); FENCE(); } while (0)

// Per-wave A fragments for K-half KK (4 x ds_read_b128).  Wave touches only
// its own A-slot (wm>>1).  Proven zero-conflict pattern: 16-row groups,
// 2-bit lg chunk, chunk XOR (row&7).
#define READ_AK(KK)                                                       \
  do { _Pragma("unroll") for (int mi = 0; mi < 4; ++mi) {                 \
    int hr = (wm & 1) * 64 + mi * 16 + l15;                               \
    const signed char* hb = lb + (wm >> 1) * SLOT_B + hr * BKB;           \
    af[mi] = *reinterpret_cast<const i32x4*>(                             \
        hb + ((((KK) * 4 + lg) ^ (hr & 7)) * 16));                        \
  } } while (0)

// Per-wave B fragments for K-half KK (4 x ds_read_b128), slot 2+(wn>>1).
#define READ_BK(KK)                                                       \
  do { _Pragma("unroll") for (int ni = 0; ni < 4; ++ni) {                 \
    int hr = (wn & 1) * 64 + ni * 16 + l15;                               \
    const signed char* hb = lb + (2 + (wn >> 1)) * SLOT_B + hr * BKB;     \
    bf[ni] = *reinterpret_cast<const i32x4*>(                             \
        hb + ((((KK) * 4 + lg) ^ (hr & 7)) * 16));                        \
  } } while (0)

// 16-MFMA cluster over the wave's 64x64 sub-tile, setprio'd (T5).
#define MFMA16()                                                          \
  do { __builtin_amdgcn_s_setprio(1);                                     \
    _Pragma("unroll") for (int mi = 0; mi < 4; ++mi)                      \
      _Pragma("unroll") for (int ni = 0; ni < 4; ++ni)                    \
        acc[mi][ni] = __builtin_amdgcn_mfma_i32_16x16x64_i8(              \
            af[mi], bf[ni], acc[mi][ni], 0, 0, 0);                        \
    __builtin_amdgcn_s_setprio(0);                                        \
  } while (0)

// C[m][o] = xs[m] * scale[o] * (int dot of Xq[m,:], Wq[o,:]) + bias[o]
// Xq:[M][K] i8, Wq:[N][K] i8 (B^T layout), C:[M][N] f32.
// 1024 threads (16 waves, 4x4 grid, 4 waves/SIMD for TLP), 256x256 tile,
// BKB=128, 2-buffer ping-pong, 1 barrier/tile, kk-split frag reads.
__global__ __launch_bounds__(1024) void gemm_kernel(
    const signed char* __restrict__ A,
    const signed char* __restrict__ B,
    const float* __restrict__ scale,
    const float* __restrict__ xs,
    const float* __restrict__ bias,
    float* __restrict__ C)
{
    extern __shared__ signed char lds[];   // 2 x 64KB

    // bijective XCD swizzle: nwg = 16*64 = 1024, divisible by 8
    const int nwg = (M_DIM / BM) * (N_DIM / BN);
    const int cpx = nwg / 8;
    int bid = blockIdx.x;
    int swz = (bid & 7) * cpx + (bid >> 3);
    const int ntn = N_DIM / BN;               // 64
    int tm = swz / ntn;
    int tn = swz % ntn;

    int tid  = threadIdx.x;
    int lane = tid & 63;
    int wid  = tid >> 6;      // 16 waves: 4 (M) x 4 (N)
    int wm   = wid >> 2;      // 0..3  (64 C-rows each)
    int wn   = wid & 3;       // 0..3  (64 C-cols each)
    int l15  = lane & 15;
    int lg   = lane >> 4;     // 0..3

    const signed char* Ab = A + (size_t)tm * BM * K_DIM;
    const signed char* Bb = B + (size_t)tn * BN * K_DIM;

    // Stage one full tile (A 256x128B + B 256x128B = 64KB) for K-tile t into
    // buffer buf: 4 gload_lds per thread, iteration i == slot (A0,A1,B0,B1).
    // Chunk swizzle ch^(r&7) on the GLOBAL source (rule #21); LDS dest linear.
    int srow = tid >> 3;                      // 0..127 within slot
    int sch  = ((tid & 7) ^ (srow & 7)) * 16; // swizzled chunk byte offset
    auto STAGE = [&](int buf, int t) {
        signed char* dbase = lds + buf * TILE_B + tid * 16;
        #pragma unroll
        for (int i = 0; i < 4; ++i) {
            const signed char* src = (i < 2)
                ? Ab + (size_t)(i * 128 + srow) * K_DIM + t * BKB + sch
                : Bb + (size_t)((i - 2) * 128 + srow) * K_DIM + t * BKB + sch;
            __builtin_amdgcn_global_load_lds(
                (const __attribute__((address_space(1))) unsigned int*)src,
                (__attribute__((address_space(3))) unsigned int*)(dbase + i * SLOT_B),
                16, 0, 0);
        }
    };

    i32x4 acc[4][4];
    #pragma unroll
    for (int mi = 0; mi < 4; ++mi)
      #pragma unroll
      for (int ni = 0; ni < 4; ++ni)
        acc[mi][ni] = (i32x4){0, 0, 0, 0};

    i32x4 af[4], bf[4];

    // Prologue: tile0 staged and published.
    STAGE(0, 0);
    asm volatile("s_waitcnt vmcnt(0)" ::: "memory");
    BARRIER();

    for (int t = 0; t < NT; ++t) {
        const signed char* lb = lds + (t & 1) * TILE_B;
        // Stage t+1 into the other buffer.  Safe: that buffer's reads all
        // completed before the barrier that ended tile t-1 (lgkm ordering
        // within each wave + barrier publication).
        if (t + 1 < NT) STAGE((t + 1) & 1, t + 1);
        READ_AK(0);
        READ_BK(0);
        MFMA16();                 // kk0: 16 MFMA
        READ_AK(1);
        READ_BK(1);
        MFMA16();                 // kk1: 16 MFMA
        // Drain own stage loads (issued a full tile body ago -> cheap),
        // then publish the buffer flip.
        asm volatile("s_waitcnt vmcnt(0)" ::: "memory");
        BARRIER();
    }

    // Epilogue: 16x16 C/D layout col = lane&15, row = (lane>>4)*4 + reg (m89)
    #pragma unroll
    for (int ni = 0; ni < 4; ++ni) {
        int col = tn * BN + wn * 64 + ni * 16 + l15;
        float s = scale[col];
        float b = bias[col];
        #pragma unroll
        for (int mi = 0; mi < 4; ++mi) {
            int row0 = tm * BM + wm * 64 + mi * 16 + lg * 4;
            float4 x4 = *reinterpret_cast<const float4*>(xs + row0);
            float xv[4] = {x4.x, x4.y, x4.z, x4.w};
            #pragma unroll
            for (int r = 0; r < 4; ++r)
                C[(size_t)(row0 + r) * N_DIM + col] =
                    (float)acc[mi][ni][r] * (s * xv[r]) + b;
        }
    }
}

// safety net if workspace is too small
__global__ void naive_kernel(const float* __restrict__ x,
                             const int* __restrict__ w,
                             const float* __restrict__ scale,
                             const float* __restrict__ bias,
                             float* __restrict__ out) {
    long long idx = (long long)blockIdx.x * blockDim.x + threadIdx.x;
    long long total = (long long)M_DIM * N_DIM;
    if (idx >= total) return;
    int m = (int)(idx / N_DIM);
    int o = (int)(idx % N_DIM);
    const float* xr = x + (size_t)m * K_DIM;
    const int* wr = w + (size_t)o * K_DIM;
    float sum = 0.f;
    for (int k = 0; k < K_DIM; ++k) sum += xr[k] * (float)wr[k];
    out[idx] = sum * scale[o] + bias[o];
}

extern "C" void kernel_launch(void* const* d_in, const int* in_sizes, int n_in,
                              void* d_out, int out_size, void* d_ws, size_t ws_size,
                              hipStream_t stream)
{
    const float* x     = (const float*)d_in[0];
    const int*   w     = (const int*)d_in[1];
    const float* scale = (const float*)d_in[2];
    const float* bias  = (const float*)d_in[3];
    float*       out   = (float*)d_out;

    const size_t needW = (size_t)N_DIM * K_DIM;            // 64MB int8
    const size_t needX = (size_t)M_DIM * K_DIM;            // 16MB int8
    const size_t needS = (size_t)M_DIM * sizeof(float);    // 16KB

    if (ws_size >= needW + needX + needS) {
        signed char* Wq = (signed char*)d_ws;
        signed char* Xq = (signed char*)((char*)d_ws + needW);
        float*       xs = (float*)((char*)d_ws + needW + needX);
        hipLaunchKernelGGL(cvt_w_kernel, dim3(2048), dim3(256), 0, stream,
                           w, Wq, N_DIM * K_DIM);
        hipLaunchKernelGGL(quant_x_kernel, dim3(M_DIM), dim3(256), 0, stream,
                           x, Xq, xs);
        hipLaunchKernelGGL(gemm_kernel, dim3((M_DIM / BM) * (N_DIM / BN)), dim3(1024),
                           LDS_BYTES, stream, Xq, Wq, scale, xs, bias, out);
    } else {
        long long total = (long long)M_DIM * N_DIM;
        int blocks = (int)((total + 255) / 256);
        hipLaunchKernelGGL(naive_kernel, dim3(blocks), dim3(256), 0, stream,
                           x, w, scale, bias, out);
    }
}